// Round 9
// baseline (222.251 us; speedup 1.0000x reference)
//
#include <hip/hip_runtime.h>
#include <hip/hip_bf16.h>

#define N_ENT    100000
#define NUM_REL  400
#define DIM      128
#define NUM_EDGES 800000
#define E_HALF   400000
#define N_RB     6250          // N_ENT/16 rowblocks

using short8 = __attribute__((ext_vector_type(8))) short;
using f32x4  = __attribute__((ext_vector_type(4))) float;

__device__ __forceinline__ float bf_lo(unsigned u) { return __uint_as_float(u << 16); }
__device__ __forceinline__ float bf_hi(unsigned u) { return __uint_as_float(u & 0xffff0000u); }
__device__ __forceinline__ unsigned short f2bf(float f) {
    unsigned u = __float_as_uint(f);
    u = u + 0x7fffu + ((u >> 16) & 1u);   // RNE
    return (unsigned short)(u >> 16);
}
__device__ __forceinline__ unsigned pack2bf(float a, float b) {
    return (unsigned)f2bf(a) | ((unsigned)f2bf(b) << 16);
}

// ---------------- dinv + segment offsets (merged) ----------------
__global__ __launch_bounds__(256) void dinv_offs_kernel(const int* __restrict__ deg,
                                                        float* __restrict__ dinv,
                                                        int* __restrict__ offs,
                                                        int* __restrict__ counter) {
    int i = blockIdx.x * 256 + threadIdx.x;
    int lane = threadIdx.x & 63;
    int v = (i < 2 * N_ENT) ? deg[i] : 0;
    if (i < 2 * N_ENT) dinv[i] = (v > 0) ? rsqrtf((float)v) : 0.0f;
    int pre = v;
    #pragma unroll
    for (int d = 1; d < 64; d <<= 1) {
        int t = __shfl_up(pre, d);
        if (lane >= d) pre += t;
    }
    int total = __shfl(pre, 63);
    int base = 0;
    if (lane == 0) base = atomicAdd(counter, total);
    base = __shfl(base, 0);
    if (i < 2 * N_ENT) offs[i] = base + pre - v;
}

// ---------------- fill CSR records {col|t<<17, norm} ----------------
__global__ __launch_bounds__(256) void fill_kernel(const int* __restrict__ rows,
                                                   const int* __restrict__ cols,
                                                   const int* __restrict__ et,
                                                   const float* __restrict__ dinv,
                                                   const int* __restrict__ offs,
                                                   int* __restrict__ cursor,
                                                   uint2* __restrict__ recs) {
    int e = blockIdx.x * 256 + threadIdx.x;
    if (e >= NUM_EDGES) return;
    int half = (e >= E_HALF) ? 1 : 0;
    int g = half * N_ENT + rows[e];
    int col = cols[e];
    int t = et[e];
    int pos = atomicAdd(&cursor[g], 1);
    float norm = dinv[g] * dinv[half * N_ENT + col];
    recs[offs[g] + pos] = make_uint2((unsigned)col | ((unsigned)t << 17),
                                     __float_as_uint(norm));
}

// ---------------- mega-prep: xb, wtfrag, rb16, cvec, rel_gemm, deg histogram ----------------
#define PB_XB   6250
#define PB_WT   (PB_XB + 24)
#define PB_RB   (PB_WT + 25)
#define PB_CV   (PB_RB + 1)
#define PB_REL  (PB_CV + 200)
#define PB_DEG  (PB_REL + 3125)
__global__ __launch_bounds__(256) void prep_kernel(const float* __restrict__ x,
                                                   const float* __restrict__ w_in,
                                                   const float* __restrict__ w_out,
                                                   const float* __restrict__ w_loop,
                                                   const float* __restrict__ r,
                                                   const float* __restrict__ loop_rel,
                                                   const float* __restrict__ w_rel,
                                                   const int* __restrict__ rows,
                                                   uint4* __restrict__ xb4,
                                                   uint4* __restrict__ wtfrag,
                                                   uint4* __restrict__ rb16,
                                                   float* __restrict__ cvec,
                                                   float* __restrict__ r_out,
                                                   int* __restrict__ deg) {
    int b = blockIdx.x;
    int t = threadIdx.x;
    if (b < PB_XB) {
        int i = b * 256 + t;
        if (i < N_ENT * 16) {
            const float* p = x + (size_t)(i >> 4) * DIM + (i & 15) * 8;
            float4 f0 = *(const float4*)p;
            float4 f1 = *(const float4*)(p + 4);
            uint4 o;
            o.x = pack2bf(f0.x, f0.y);
            o.y = pack2bf(f0.z, f0.w);
            o.z = pack2bf(f1.x, f1.y);
            o.w = pack2bf(f1.z, f1.w);
            xb4[i] = o;
        }
    } else if (b < PB_WT) {
        int j = (b - PB_XB) * 256 + t;
        if (j < 8 * 12 * 64) {
            int lane = j & 63;
            int kb = (j >> 6) % 12;
            int nblk = j / 768;
            int n = nblk * 16 + (lane & 15);
            int s = kb >> 2;
            int klo = (kb & 3) * 32 + (lane >> 4) * 8;    // 0..127 within slice
            const float* W = (s == 0) ? w_in : (s == 1) ? w_out : w_loop;
            float v[8];
            #pragma unroll
            for (int e = 0; e < 8; ++e) v[e] = W[(klo + e) * DIM + n];
            uint4 o;
            o.x = pack2bf(v[0], v[1]);
            o.y = pack2bf(v[2], v[3]);
            o.z = pack2bf(v[4], v[5]);
            o.w = pack2bf(v[6], v[7]);
            wtfrag[j] = o;
        }
    } else if (b < PB_RB) {
        int k = (b - PB_WT) * 256 + t;
        if (k < NUM_REL * 16) {
            const float* p = r + (size_t)(k >> 4) * DIM + (k & 15) * 8;
            float4 f0 = *(const float4*)p;
            float4 f1 = *(const float4*)(p + 4);
            uint4 o;
            o.x = pack2bf(f0.x, f0.y);
            o.y = pack2bf(f0.z, f0.w);
            o.z = pack2bf(f1.x, f1.y);
            o.w = pack2bf(f1.z, f1.w);
            rb16[k] = o;
        }
    } else if (b < PB_CV) {
        if (t < 128) {
            float acc = 0.0f;
            #pragma unroll 8
            for (int k = 0; k < DIM; ++k)
                acc += loop_rel[k] * w_loop[k * DIM + t];
            cvec[t] = acc;
        }
    } else if (b < PB_REL) {
        int row = (b - PB_CV) * 2 + (t >> 7);
        int col = t & 127;
        const float* rr = r + (size_t)row * DIM;
        float acc = 0.0f;
        #pragma unroll 8
        for (int k = 0; k < DIM; ++k)
            acc += rr[k] * w_rel[k * DIM + col];
        r_out[(size_t)row * DIM + col] = acc;
    } else {
        int e = (b - PB_REL) * 256 + t;
        if (e < NUM_EDGES) {
            int half = (e >= E_HALF) ? 1 : 0;
            atomicAdd(&deg[half * N_ENT + rows[e]], 1);
        }
    }
}

// ---------------- fused gather + MFMA GEMM ----------------
// Per 64-row block: gather 128 (row,half) segments into XOR-swizzled LDS,
// barrier, then out = tanh((aggA@Win + aggB@Wout + x@Wloop - cvec)/3 + bias).
// 4 waves 2x2: wave = 32 rows x 64 cols.
#define ACC8(X, V, NRM)                                        \
    acc[0] += (NRM) * (bf_lo((X).x) - bf_lo((V).x));           \
    acc[1] += (NRM) * (bf_hi((X).x) - bf_hi((V).x));           \
    acc[2] += (NRM) * (bf_lo((X).y) - bf_lo((V).y));           \
    acc[3] += (NRM) * (bf_hi((X).y) - bf_hi((V).y));           \
    acc[4] += (NRM) * (bf_lo((X).z) - bf_lo((V).z));           \
    acc[5] += (NRM) * (bf_hi((X).z) - bf_hi((V).z));           \
    acc[6] += (NRM) * (bf_lo((X).w) - bf_lo((V).w));           \
    acc[7] += (NRM) * (bf_hi((X).w) - bf_hi((V).w));

__global__ __launch_bounds__(256) void fused_gg_kernel(const int* __restrict__ offs,
                                                       const int* __restrict__ deg,
                                                       const uint2* __restrict__ recs,
                                                       const unsigned short* __restrict__ xb,
                                                       const unsigned short* __restrict__ rb16,
                                                       const uint4* __restrict__ wtfrag,
                                                       const float* __restrict__ bias,
                                                       const float* __restrict__ cvec,
                                                       float* __restrict__ out) {
    __shared__ uint4 Alds4[2048];            // 32 KB: [128 segs][256 B], XOR-swizzled
    char* Alds = (char*)Alds4;

    int tid = threadIdx.x;
    int row0 = blockIdx.x * 64;

    // ---------- gather phase: 16 groups x 16 lanes; 8 segs per group ----------
    {
        int grp = tid >> 4;
        int c = tid & 15;                    // 16 B chunk index within seg row
        #pragma unroll
        for (int i = 0; i < 8; ++i) {
            int sl = i * 16 + grp;           // seg-local 0..127
            int half = sl >> 6;
            int row = row0 + (sl & 63);
            float acc[8] = {0.f, 0.f, 0.f, 0.f, 0.f, 0.f, 0.f, 0.f};
            if (row < N_ENT) {
                int g = half * N_ENT + row;
                int e = offs[g];
                int end = e + deg[g];
                for (; e + 4 <= end; e += 4) {
                    uint2 r0 = recs[e];
                    uint2 r1 = recs[e + 1];
                    uint2 r2 = recs[e + 2];
                    uint2 r3 = recs[e + 3];
                    uint4 x0 = ((const uint4*)(xb + (size_t)(r0.x & 0x1ffff) * DIM))[c];
                    uint4 v0 = ((const uint4*)(rb16 + (size_t)(r0.x >> 17) * DIM))[c];
                    uint4 x1 = ((const uint4*)(xb + (size_t)(r1.x & 0x1ffff) * DIM))[c];
                    uint4 v1 = ((const uint4*)(rb16 + (size_t)(r1.x >> 17) * DIM))[c];
                    uint4 x2 = ((const uint4*)(xb + (size_t)(r2.x & 0x1ffff) * DIM))[c];
                    uint4 v2 = ((const uint4*)(rb16 + (size_t)(r2.x >> 17) * DIM))[c];
                    uint4 x3 = ((const uint4*)(xb + (size_t)(r3.x & 0x1ffff) * DIM))[c];
                    uint4 v3 = ((const uint4*)(rb16 + (size_t)(r3.x >> 17) * DIM))[c];
                    float n0 = __uint_as_float(r0.y);
                    float n1 = __uint_as_float(r1.y);
                    float n2 = __uint_as_float(r2.y);
                    float n3 = __uint_as_float(r3.y);
                    ACC8(x0, v0, n0)
                    ACC8(x1, v1, n1)
                    ACC8(x2, v2, n2)
                    ACC8(x3, v3, n3)
                }
                for (; e < end; ++e) {
                    uint2 rA = recs[e];
                    uint4 xA = ((const uint4*)(xb + (size_t)(rA.x & 0x1ffff) * DIM))[c];
                    uint4 vA = ((const uint4*)(rb16 + (size_t)(rA.x >> 17) * DIM))[c];
                    float nA = __uint_as_float(rA.y);
                    ACC8(xA, vA, nA)
                }
            }
            uint4 o;
            o.x = pack2bf(acc[0], acc[1]);
            o.y = pack2bf(acc[2], acc[3]);
            o.z = pack2bf(acc[4], acc[5]);
            o.w = pack2bf(acc[6], acc[7]);
            int byteoff = sl * 256 + ((c * 16) ^ ((sl & 7) << 4));
            *(uint4*)(Alds + byteoff) = o;
        }
    }
    __syncthreads();

    // ---------- MFMA phase ----------
    int wave = tid >> 6;
    int lane = tid & 63;
    int wm = wave >> 1, wn = wave & 1;
    int lr = lane & 15;
    int ks = lane >> 4;                      // 0..3

    f32x4 acc[2][4];
    #pragma unroll
    for (int mi = 0; mi < 2; ++mi)
        #pragma unroll
        for (int ni = 0; ni < 4; ++ni)
            acc[mi][ni] = (f32x4){0.f, 0.f, 0.f, 0.f};

    #pragma unroll
    for (int kb = 0; kb < 12; ++kb) {
        int s = kb >> 2, kq = kb & 3;
        short8 a[2], b[4];
        #pragma unroll
        for (int ni = 0; ni < 4; ++ni) {
            uint4 u = wtfrag[((wn * 4 + ni) * 12 + kb) * 64 + lane];
            b[ni] = *(short8*)&u;
        }
        #pragma unroll
        for (int mi = 0; mi < 2; ++mi) {
            if (s < 2) {
                int sl = s * 64 + wm * 32 + mi * 16 + lr;
                int addr = sl * 256 + (((kq * 64) + (ks * 16)) ^ ((sl & 7) << 4));
                a[mi] = *(const short8*)(Alds + addr);
            } else {
                int row = row0 + wm * 32 + mi * 16 + lr;
                if (row > N_ENT - 1) row = N_ENT - 1;
                uint4 u = *(const uint4*)(xb + (size_t)row * DIM + kq * 32 + ks * 8);
                a[mi] = *(short8*)&u;
            }
        }
        #pragma unroll
        for (int mi = 0; mi < 2; ++mi)
            #pragma unroll
            for (int ni = 0; ni < 4; ++ni)
                acc[mi][ni] = __builtin_amdgcn_mfma_f32_16x16x32_bf16(a[mi], b[ni], acc[mi][ni], 0, 0, 0);
    }

    int col0 = wn * 64;
    int row0w = row0 + wm * 32;
    const float third = 1.0f / 3.0f;
    float bb[4];
    #pragma unroll
    for (int ni = 0; ni < 4; ++ni) {
        int col = col0 + ni * 16 + lr;
        bb[ni] = bias[col] - third * cvec[col];
    }

    #pragma unroll
    for (int mi = 0; mi < 2; ++mi) {
        #pragma unroll
        for (int reg = 0; reg < 4; ++reg) {
            int grow = row0w + mi * 16 + ks * 4 + reg;
            if (grow < N_ENT) {
                #pragma unroll
                for (int ni = 0; ni < 4; ++ni)
                    out[(size_t)grow * DIM + col0 + ni * 16 + lr] =
                        tanhf(acc[mi][ni][reg] * third + bb[ni]);
            }
        }
    }
}

extern "C" void kernel_launch(void* const* d_in, const int* in_sizes, int n_in,
                              void* d_out, int out_size, void* d_ws, size_t ws_size,
                              hipStream_t stream) {
    const float* x        = (const float*)d_in[0];
    const float* r        = (const float*)d_in[1];
    const int*   ei       = (const int*)d_in[2];   // [2][800000]: rows then cols
    const int*   et       = (const int*)d_in[3];
    const float* w_in     = (const float*)d_in[4];
    const float* w_out    = (const float*)d_in[5];
    const float* w_loop   = (const float*)d_in[6];
    const float* w_rel    = (const float*)d_in[7];
    const float* loop_rel = (const float*)d_in[8];
    const float* bias     = (const float*)d_in[9];

    float* out   = (float*)d_out;            // 100000*128
    float* r_out = out + (size_t)N_ENT * DIM;

    // -------- workspace layout --------
    unsigned short* xb   = (unsigned short*)d_ws;            // [N][128] bf16 row-major
    unsigned short* wtf  = xb + (size_t)N_ENT * DIM;         // 8*12*64*8 bf16 frag-order
    unsigned short* rb16 = wtf + 8 * 12 * 64 * 8;            // [400][128] bf16
    uint2* recs = (uint2*)(rb16 + NUM_REL * DIM);            // 800k x 8 B
    int*   deg     = (int*)(recs + NUM_EDGES);               // 2N
    int*   cursor  = deg + 2 * N_ENT;                        // 2N
    int*   counter = cursor + 2 * N_ENT;                     // 1 (+3 pad)
    int*   offs    = counter + 4;                            // 2N
    float* dinv    = (float*)(offs + 2 * N_ENT);             // 2N
    float* cvec    = dinv + 2 * N_ENT;                       // 128

    const int* rows = ei;
    const int* cols = ei + NUM_EDGES;

    hipMemsetAsync(deg, 0, (4ull * N_ENT + 4) * sizeof(int), stream);

    prep_kernel<<<PB_DEG, 256, 0, stream>>>(
        x, w_in, w_out, w_loop, r, loop_rel, w_rel, rows,
        (uint4*)xb, (uint4*)wtf, (uint4*)rb16, cvec, r_out, deg);

    dinv_offs_kernel<<<(2 * N_ENT + 255) / 256, 256, 0, stream>>>(deg, dinv, offs, counter);
    fill_kernel<<<(NUM_EDGES + 255) / 256, 256, 0, stream>>>(rows, cols, et, dinv, offs, cursor, recs);

    fused_gg_kernel<<<(N_ENT + 63) / 64, 256, 0, stream>>>(
        offs, deg, recs, xb, rb16, (const uint4*)wtf, bias, cvec, out);
}

// Round 10
// 210.222 us; speedup vs baseline: 1.0572x; 1.0572x over previous
//
#include <hip/hip_runtime.h>
#include <hip/hip_bf16.h>

#define N_ENT    100000
#define NUM_REL  400
#define DIM      128
#define NUM_EDGES 800000
#define E_HALF   400000
#define N_RB     6250          // N_ENT/16 rowblocks

using short8 = __attribute__((ext_vector_type(8))) short;
using f32x4  = __attribute__((ext_vector_type(4))) float;

__device__ __forceinline__ float bf_lo(unsigned u) { return __uint_as_float(u << 16); }
__device__ __forceinline__ float bf_hi(unsigned u) { return __uint_as_float(u & 0xffff0000u); }
__device__ __forceinline__ unsigned short f2bf(float f) {
    unsigned u = __float_as_uint(f);
    u = u + 0x7fffu + ((u >> 16) & 1u);   // RNE
    return (unsigned short)(u >> 16);
}
__device__ __forceinline__ unsigned pack2bf(float a, float b) {
    return (unsigned)f2bf(a) | ((unsigned)f2bf(b) << 16);
}

// ---------------- dinv + segment offsets (merged) ----------------
__global__ __launch_bounds__(256) void dinv_offs_kernel(const int* __restrict__ deg,
                                                        float* __restrict__ dinv,
                                                        int* __restrict__ offs,
                                                        int* __restrict__ counter) {
    int i = blockIdx.x * 256 + threadIdx.x;
    int lane = threadIdx.x & 63;
    int v = (i < 2 * N_ENT) ? deg[i] : 0;
    if (i < 2 * N_ENT) dinv[i] = (v > 0) ? rsqrtf((float)v) : 0.0f;
    int pre = v;
    #pragma unroll
    for (int d = 1; d < 64; d <<= 1) {
        int t = __shfl_up(pre, d);
        if (lane >= d) pre += t;
    }
    int total = __shfl(pre, 63);
    int base = 0;
    if (lane == 0) base = atomicAdd(counter, total);
    base = __shfl(base, 0);
    if (i < 2 * N_ENT) offs[i] = base + pre - v;
}

// ---------------- fill CSR records {col|t<<17, norm} ----------------
__global__ __launch_bounds__(256) void fill_kernel(const int* __restrict__ rows,
                                                   const int* __restrict__ cols,
                                                   const int* __restrict__ et,
                                                   const float* __restrict__ dinv,
                                                   const int* __restrict__ offs,
                                                   int* __restrict__ cursor,
                                                   uint2* __restrict__ recs) {
    int e = blockIdx.x * 256 + threadIdx.x;
    if (e >= NUM_EDGES) return;
    int half = (e >= E_HALF) ? 1 : 0;
    int g = half * N_ENT + rows[e];
    int col = cols[e];
    int t = et[e];
    int pos = atomicAdd(&cursor[g], 1);
    float norm = dinv[g] * dinv[half * N_ENT + col];
    recs[offs[g] + pos] = make_uint2((unsigned)col | ((unsigned)t << 17),
                                     __float_as_uint(norm));
}

// ---------------- mega-prep: xb, wtfrag, rb16, cvec, rel_gemm, deg histogram ----------------
#define PB_XB   6250
#define PB_WT   (PB_XB + 24)
#define PB_RB   (PB_WT + 25)
#define PB_CV   (PB_RB + 1)
#define PB_REL  (PB_CV + 200)
#define PB_DEG  (PB_REL + 3125)
__global__ __launch_bounds__(256) void prep_kernel(const float* __restrict__ x,
                                                   const float* __restrict__ w_in,
                                                   const float* __restrict__ w_out,
                                                   const float* __restrict__ w_loop,
                                                   const float* __restrict__ r,
                                                   const float* __restrict__ loop_rel,
                                                   const float* __restrict__ w_rel,
                                                   const int* __restrict__ rows,
                                                   uint4* __restrict__ xb4,
                                                   uint4* __restrict__ wtfrag,
                                                   uint4* __restrict__ rb16,
                                                   float* __restrict__ cvec,
                                                   float* __restrict__ r_out,
                                                   int* __restrict__ deg) {
    int b = blockIdx.x;
    int t = threadIdx.x;
    if (b < PB_XB) {
        int i = b * 256 + t;
        if (i < N_ENT * 16) {
            const float* p = x + (size_t)(i >> 4) * DIM + (i & 15) * 8;
            float4 f0 = *(const float4*)p;
            float4 f1 = *(const float4*)(p + 4);
            uint4 o;
            o.x = pack2bf(f0.x, f0.y);
            o.y = pack2bf(f0.z, f0.w);
            o.z = pack2bf(f1.x, f1.y);
            o.w = pack2bf(f1.z, f1.w);
            xb4[i] = o;
        }
    } else if (b < PB_WT) {
        int j = (b - PB_XB) * 256 + t;
        if (j < 8 * 12 * 64) {
            int lane = j & 63;
            int kb = (j >> 6) % 12;
            int nblk = j / 768;
            int n = nblk * 16 + (lane & 15);
            int s = kb >> 2;
            int klo = (kb & 3) * 32 + (lane >> 4) * 8;    // 0..127 within slice
            const float* W = (s == 0) ? w_in : (s == 1) ? w_out : w_loop;
            float v[8];
            #pragma unroll
            for (int e = 0; e < 8; ++e) v[e] = W[(klo + e) * DIM + n];
            uint4 o;
            o.x = pack2bf(v[0], v[1]);
            o.y = pack2bf(v[2], v[3]);
            o.z = pack2bf(v[4], v[5]);
            o.w = pack2bf(v[6], v[7]);
            wtfrag[j] = o;
        }
    } else if (b < PB_RB) {
        int k = (b - PB_WT) * 256 + t;
        if (k < NUM_REL * 16) {
            const float* p = r + (size_t)(k >> 4) * DIM + (k & 15) * 8;
            float4 f0 = *(const float4*)p;
            float4 f1 = *(const float4*)(p + 4);
            uint4 o;
            o.x = pack2bf(f0.x, f0.y);
            o.y = pack2bf(f0.z, f0.w);
            o.z = pack2bf(f1.x, f1.y);
            o.w = pack2bf(f1.z, f1.w);
            rb16[k] = o;
        }
    } else if (b < PB_CV) {
        if (t < 128) {
            float acc = 0.0f;
            #pragma unroll 8
            for (int k = 0; k < DIM; ++k)
                acc += loop_rel[k] * w_loop[k * DIM + t];
            cvec[t] = acc;
        }
    } else if (b < PB_REL) {
        int row = (b - PB_CV) * 2 + (t >> 7);
        int col = t & 127;
        const float* rr = r + (size_t)row * DIM;
        float acc = 0.0f;
        #pragma unroll 8
        for (int k = 0; k < DIM; ++k)
            acc += rr[k] * w_rel[k * DIM + col];
        r_out[(size_t)row * DIM + col] = acc;
    } else {
        int e = (b - PB_REL) * 256 + t;
        if (e < NUM_EDGES) {
            int half = (e >= E_HALF) ? 1 : 0;
            atomicAdd(&deg[half * N_ENT + rows[e]], 1);
        }
    }
}

// ---------------- gather-aggregate -> aggfrag (MFMA fragment order) ----------------
#define ACC8(X, V, NRM)                                        \
    acc[0] += (NRM) * (bf_lo((X).x) - bf_lo((V).x));           \
    acc[1] += (NRM) * (bf_hi((X).x) - bf_hi((V).x));           \
    acc[2] += (NRM) * (bf_lo((X).y) - bf_lo((V).y));           \
    acc[3] += (NRM) * (bf_hi((X).y) - bf_hi((V).y));           \
    acc[4] += (NRM) * (bf_lo((X).z) - bf_lo((V).z));           \
    acc[5] += (NRM) * (bf_hi((X).z) - bf_hi((V).z));           \
    acc[6] += (NRM) * (bf_lo((X).w) - bf_lo((V).w));           \
    acc[7] += (NRM) * (bf_hi((X).w) - bf_hi((V).w));

__global__ __launch_bounds__(256) void gather_agg_kernel(const int* __restrict__ offs,
                                                         const int* __restrict__ deg,
                                                         const uint2* __restrict__ recs,
                                                         const unsigned short* __restrict__ xb,
                                                         const unsigned short* __restrict__ rb16,
                                                         uint4* __restrict__ aggfrag) {
    int gid = blockIdx.x * 256 + threadIdx.x;
    int g = gid >> 4;
    if (g >= 2 * N_ENT) return;
    int c = gid & 15;                    // lane covers 16 B = 8 bf16 (k = c*8..c*8+7)
    int e = offs[g];
    int end = e + deg[g];
    float acc[8] = {0.f, 0.f, 0.f, 0.f, 0.f, 0.f, 0.f, 0.f};
    for (; e + 4 <= end; e += 4) {
        uint2 r0 = recs[e];
        uint2 r1 = recs[e + 1];
        uint2 r2 = recs[e + 2];
        uint2 r3 = recs[e + 3];
        uint4 x0 = ((const uint4*)(xb + (size_t)(r0.x & 0x1ffff) * DIM))[c];
        uint4 v0 = ((const uint4*)(rb16 + (size_t)(r0.x >> 17) * DIM))[c];
        uint4 x1 = ((const uint4*)(xb + (size_t)(r1.x & 0x1ffff) * DIM))[c];
        uint4 v1 = ((const uint4*)(rb16 + (size_t)(r1.x >> 17) * DIM))[c];
        uint4 x2 = ((const uint4*)(xb + (size_t)(r2.x & 0x1ffff) * DIM))[c];
        uint4 v2 = ((const uint4*)(rb16 + (size_t)(r2.x >> 17) * DIM))[c];
        uint4 x3 = ((const uint4*)(xb + (size_t)(r3.x & 0x1ffff) * DIM))[c];
        uint4 v3 = ((const uint4*)(rb16 + (size_t)(r3.x >> 17) * DIM))[c];
        float n0 = __uint_as_float(r0.y);
        float n1 = __uint_as_float(r1.y);
        float n2 = __uint_as_float(r2.y);
        float n3 = __uint_as_float(r3.y);
        ACC8(x0, v0, n0)
        ACC8(x1, v1, n1)
        ACC8(x2, v2, n2)
        ACC8(x3, v3, n3)
    }
    for (; e < end; ++e) {
        uint2 rA = recs[e];
        uint4 xA = ((const uint4*)(xb + (size_t)(rA.x & 0x1ffff) * DIM))[c];
        uint4 vA = ((const uint4*)(rb16 + (size_t)(rA.x >> 17) * DIM))[c];
        float nA = __uint_as_float(rA.y);
        ACC8(xA, vA, nA)
    }
    uint4 o;
    o.x = pack2bf(acc[0], acc[1]);
    o.y = pack2bf(acc[2], acc[3]);
    o.z = pack2bf(acc[4], acc[5]);
    o.w = pack2bf(acc[6], acc[7]);
    // fragment-order store: rowblk=g>>4, kq=c>>2, ksub=c&3, lr=g&15
    aggfrag[(((g >> 4) * 4 + (c >> 2)) * 64) + (c & 3) * 16 + (g & 15)] = o;
}

// ---------------- MFMA GEMM, fragment-direct, split-K2 ----------------
// out = tanh((aggA@Win + aggB@Wout + x@Wloop - cvec)/3 + bias)
// M=100000, N=128, K=384. Block = 32 rows x 128 cols, 4 waves (wn, kh):
// wn = col half (64), kh = K half (192). kh=1 partials -> LDS -> kh=0 adds.
__global__ __launch_bounds__(256) void mfma_gemm_kernel(const uint4* __restrict__ aggfrag,
                                                        const unsigned short* __restrict__ xb,
                                                        const uint4* __restrict__ wtfrag,
                                                        const float* __restrict__ bias,
                                                        const float* __restrict__ cvec,
                                                        float* __restrict__ out) {
    __shared__ float plds[2][32][65];      // 16.6 KB, stride-65 rows (bank-safe)

    int tid = threadIdx.x;
    int wave = tid >> 6;
    int lane = tid & 63;
    int wn = wave & 1;                     // col half
    int kh = wave >> 1;                    // K half
    int lr = lane & 15;
    int ks = lane >> 4;                    // 0..3
    int rbb = blockIdx.x * 2;              // 2 rowblocks of 16 per block (exact: 3125*32=100000)
    int row0 = blockIdx.x * 32;

    f32x4 acc[2][4];
    #pragma unroll
    for (int mi = 0; mi < 2; ++mi)
        #pragma unroll
        for (int ni = 0; ni < 4; ++ni)
            acc[mi][ni] = (f32x4){0.f, 0.f, 0.f, 0.f};

    #pragma unroll
    for (int j = 0; j < 6; ++j) {
        int kb = kh * 6 + j;
        int s = kb >> 2, kq = kb & 3;
        short8 a[2], b[4];
        #pragma unroll
        for (int ni = 0; ni < 4; ++ni) {
            uint4 u = wtfrag[((wn * 4 + ni) * 12 + kb) * 64 + lane];
            b[ni] = *(short8*)&u;
        }
        #pragma unroll
        for (int mi = 0; mi < 2; ++mi) {
            uint4 u;
            if (s < 2) {
                u = aggfrag[((size_t)(rbb + mi + s * N_RB) * 4 + kq) * 64 + lane];
            } else {
                int row = (rbb + mi) * 16 + lr;
                u = *(const uint4*)(xb + (size_t)row * DIM + kq * 32 + ks * 8);
            }
            a[mi] = *(short8*)&u;
        }
        #pragma unroll
        for (int mi = 0; mi < 2; ++mi)
            #pragma unroll
            for (int ni = 0; ni < 4; ++ni)
                acc[mi][ni] = __builtin_amdgcn_mfma_f32_16x16x32_bf16(a[mi], b[ni], acc[mi][ni], 0, 0, 0);
    }

    // kh=1 waves deposit partials
    if (kh == 1) {
        #pragma unroll
        for (int mi = 0; mi < 2; ++mi)
            #pragma unroll
            for (int ni = 0; ni < 4; ++ni)
                #pragma unroll
                for (int reg = 0; reg < 4; ++reg)
                    plds[wn][mi * 16 + ks * 4 + reg][ni * 16 + lr] = acc[mi][ni][reg];
    }
    __syncthreads();
    if (kh == 1) return;

    int col0 = wn * 64;
    const float third = 1.0f / 3.0f;
    float bb[4];
    #pragma unroll
    for (int ni = 0; ni < 4; ++ni) {
        int col = col0 + ni * 16 + lr;
        bb[ni] = bias[col] - third * cvec[col];
    }

    #pragma unroll
    for (int mi = 0; mi < 2; ++mi) {
        #pragma unroll
        for (int reg = 0; reg < 4; ++reg) {
            int rl = mi * 16 + ks * 4 + reg;
            int grow = row0 + rl;
            #pragma unroll
            for (int ni = 0; ni < 4; ++ni) {
                float v = acc[mi][ni][reg] + plds[wn][rl][ni * 16 + lr];
                out[(size_t)grow * DIM + col0 + ni * 16 + lr] = tanhf(v * third + bb[ni]);
            }
        }
    }
}

extern "C" void kernel_launch(void* const* d_in, const int* in_sizes, int n_in,
                              void* d_out, int out_size, void* d_ws, size_t ws_size,
                              hipStream_t stream) {
    const float* x        = (const float*)d_in[0];
    const float* r        = (const float*)d_in[1];
    const int*   ei       = (const int*)d_in[2];   // [2][800000]: rows then cols
    const int*   et       = (const int*)d_in[3];
    const float* w_in     = (const float*)d_in[4];
    const float* w_out    = (const float*)d_in[5];
    const float* w_loop   = (const float*)d_in[6];
    const float* w_rel    = (const float*)d_in[7];
    const float* loop_rel = (const float*)d_in[8];
    const float* bias     = (const float*)d_in[9];

    float* out   = (float*)d_out;            // 100000*128
    float* r_out = out + (size_t)N_ENT * DIM;

    // -------- workspace layout --------
    unsigned short* aggf = (unsigned short*)d_ws;            // [2N*128] bf16 frag-order
    unsigned short* xb   = aggf + 2ull * N_ENT * DIM;        // [N][128] bf16 row-major
    unsigned short* wtf  = xb + (size_t)N_ENT * DIM;         // 8*12*64*8 bf16 frag-order
    unsigned short* rb16 = wtf + 8 * 12 * 64 * 8;            // [400][128] bf16
    uint2* recs = (uint2*)(rb16 + NUM_REL * DIM);            // 800k x 8 B
    int*   deg     = (int*)(recs + NUM_EDGES);               // 2N
    int*   cursor  = deg + 2 * N_ENT;                        // 2N
    int*   counter = cursor + 2 * N_ENT;                     // 1 (+3 pad)
    int*   offs    = counter + 4;                            // 2N
    float* dinv    = (float*)(offs + 2 * N_ENT);             // 2N
    float* cvec    = dinv + 2 * N_ENT;                       // 128

    const int* rows = ei;
    const int* cols = ei + NUM_EDGES;

    hipMemsetAsync(deg, 0, (4ull * N_ENT + 4) * sizeof(int), stream);

    prep_kernel<<<PB_DEG, 256, 0, stream>>>(
        x, w_in, w_out, w_loop, r, loop_rel, w_rel, rows,
        (uint4*)xb, (uint4*)wtf, (uint4*)rb16, cvec, r_out, deg);

    dinv_offs_kernel<<<(2 * N_ENT + 255) / 256, 256, 0, stream>>>(deg, dinv, offs, counter);
    fill_kernel<<<(NUM_EDGES + 255) / 256, 256, 0, stream>>>(rows, cols, et, dinv, offs, cursor, recs);

    gather_agg_kernel<<<(2 * N_ENT * 16 + 255) / 256, 256, 0, stream>>>(
        offs, deg, recs, xb, rb16, (uint4*)aggf);

    mfma_gemm_kernel<<<N_ENT / 32, 256, 0, stream>>>(
        (const uint4*)aggf, xb, (const uint4*)wtf, bias, cvec, out);
}